// Round 1
// baseline (775.311 us; speedup 1.0000x reference)
//
#include <hip/hip_runtime.h>
#include <hip/hip_bf16.h>
#include <math.h>

// Problem constants
constexpr int B_   = 2;
constexpr int L_   = 1024;
constexpr int DM   = 1024;   // d_model
constexpr int DI   = 2048;   // d_inner
constexpr int NS   = 16;     // d_state
constexpr int DTR  = 64;     // dt_rank
constexpr int TOK  = B_ * L_;  // 2048 tokens

__device__ __forceinline__ float sigmoidf_(float v) {
    return 1.f / (1.f + __expf(-v));
}
__device__ __forceinline__ float softplusf_(float v) {
    // numerically stable softplus
    return fmaxf(v, 0.f) + __logf(1.f + __expf(-fabsf(v)));
}

// ---------------- RMSNorm ----------------
// one block per token row; 256 threads * float4 = 1024 elements
__global__ __launch_bounds__(256) void k_rmsnorm(
    const float* __restrict__ x, const float* __restrict__ w,
    float* __restrict__ h)
{
    int row = blockIdx.x;
    const float4* xr = (const float4*)(x + (size_t)row * DM);
    float4 v = xr[threadIdx.x];
    float ss = v.x*v.x + v.y*v.y + v.z*v.z + v.w*v.w;
    #pragma unroll
    for (int m = 32; m >= 1; m >>= 1) ss += __shfl_xor(ss, m);
    __shared__ float acc[4];
    int wid = threadIdx.x >> 6, lane = threadIdx.x & 63;
    if (lane == 0) acc[wid] = ss;
    __syncthreads();
    float tot = acc[0] + acc[1] + acc[2] + acc[3];
    float sc = rsqrtf(tot * (1.f / DM) + 1e-5f);
    float4 wv = ((const float4*)w)[threadIdx.x];
    float4 o;
    o.x = v.x * sc * wv.x; o.y = v.y * sc * wv.y;
    o.z = v.z * sc * wv.z; o.w = v.w * sc * wv.w;
    ((float4*)(h + (size_t)row * DM))[threadIdx.x] = o;
}

// ---------------- Generic tiled fp32 GEMM: C[M,N] = A[M,K] * B[N,K]^T ----------------
// EPI: 0 = plain store, 1 = bias + softplus, 2 = + residual, 3 = atomicAdd (split-K)
// BM=BN=64, BK=16, 256 threads, 4x4 micro-tile per thread.
template<int EPI>
__global__ __launch_bounds__(256) void k_gemm_nt(
    const float* __restrict__ A, int lda,
    const float* __restrict__ Bm, int ldb,
    float* __restrict__ C, int ldc,
    int M, int N, int K_chunk,
    const float* __restrict__ bias, const float* __restrict__ resid)
{
    __shared__ float As[16][68];   // k-major, +4 pad (keeps float4 alignment)
    __shared__ float Bs[16][68];

    int tid = threadIdx.x;
    int m0 = blockIdx.y * 64;
    int n0 = blockIdx.x * 64;
    int kbase = blockIdx.z * K_chunk;

    int lr = tid >> 2;   // 0..63 row-in-tile for loads
    int lq = tid & 3;    // k-quarter
    int ty = tid >> 4;   // 0..15
    int tx = tid & 15;   // 0..15

    float acc[4][4] = {};

    const float* Aptr = A + (size_t)(m0 + lr) * lda + kbase + lq * 4;
    int bn = n0 + lr;
    bool bvalid = bn < N;
    const float* Bptr = Bm + (size_t)(bvalid ? bn : 0) * ldb + kbase + lq * 4;

    for (int k0 = 0; k0 < K_chunk; k0 += 16) {
        float4 av = *(const float4*)(Aptr + k0);
        float4 bv = bvalid ? *(const float4*)(Bptr + k0)
                           : make_float4(0.f, 0.f, 0.f, 0.f);
        __syncthreads();
        As[lq*4+0][lr] = av.x; As[lq*4+1][lr] = av.y;
        As[lq*4+2][lr] = av.z; As[lq*4+3][lr] = av.w;
        Bs[lq*4+0][lr] = bv.x; Bs[lq*4+1][lr] = bv.y;
        Bs[lq*4+2][lr] = bv.z; Bs[lq*4+3][lr] = bv.w;
        __syncthreads();
        #pragma unroll
        for (int kk = 0; kk < 16; kk++) {
            float av_[4], bv_[4];
            *(float4*)av_ = *(const float4*)&As[kk][ty * 4];
            *(float4*)bv_ = *(const float4*)&Bs[kk][tx * 4];
            #pragma unroll
            for (int i = 0; i < 4; i++)
                #pragma unroll
                for (int j = 0; j < 4; j++)
                    acc[i][j] = fmaf(av_[i], bv_[j], acc[i][j]);
        }
    }

    int col = n0 + tx * 4;
    #pragma unroll
    for (int i = 0; i < 4; i++) {
        int row = m0 + ty * 4 + i;
        if constexpr (EPI == 3) {
            #pragma unroll
            for (int j = 0; j < 4; j++)
                if (col + j < N)
                    atomicAdd(&C[(size_t)row * ldc + col + j], acc[i][j]);
        } else {
            float vv[4];
            #pragma unroll
            for (int j = 0; j < 4; j++) {
                float t = acc[i][j];
                if constexpr (EPI == 1) t = softplusf_(t + bias[col + j]);
                if constexpr (EPI == 2) t += resid[(size_t)row * ldc + col + j];
                vv[j] = t;
            }
            *(float4*)&C[(size_t)row * ldc + col] = *(float4*)vv;
        }
    }
}

// ---------------- causal depthwise conv1d (K=4) + bias + SiLU ----------------
// xs = first half of x_and_res rows (row stride 2*DI). One float4 of d per thread.
__global__ __launch_bounds__(256) void k_conv_silu(
    const float* __restrict__ xr, const float* __restrict__ w,
    const float* __restrict__ bconv, float* __restrict__ u)
{
    int idx = blockIdx.x * 256 + threadIdx.x;  // B*L*(DI/4) = 1,048,576
    int dq = idx & 511;
    int l  = (idx >> 9) & 1023;
    int bb = idx >> 19;
    int dd = dq * 4;

    float4 wrow[4];
    #pragma unroll
    for (int j = 0; j < 4; j++)
        wrow[j] = *(const float4*)&w[(dd + j) * 4];   // [d][4 taps]
    float4 bias4 = *(const float4*)&bconv[dd];

    float acc[4] = { bias4.x, bias4.y, bias4.z, bias4.w };
    #pragma unroll
    for (int k = 0; k < 4; k++) {
        int lp = l - 3 + k;
        if (lp >= 0) {
            const float4 xv = *(const float4*)
                &xr[((size_t)(bb * L_ + lp)) * (2 * DI) + dd];
            const float xs_[4] = { xv.x, xv.y, xv.z, xv.w };
            #pragma unroll
            for (int j = 0; j < 4; j++)
                acc[j] = fmaf(xs_[j], ((const float*)&wrow[j])[k], acc[j]);
        }
    }
    float out[4];
    #pragma unroll
    for (int j = 0; j < 4; j++)
        out[j] = acc[j] * sigmoidf_(acc[j]);
    *(float4*)&u[((size_t)(bb * L_ + l)) * DI + dd] = *(float4*)out;
}

// ---------------- selective scan ----------------
// block = (b, 16 channels); 256 threads = 16 ch * 16 states.
// Stages of 16 timesteps staged through double-buffered LDS with register prefetch.
// Writes gated output y = (scan_y + u*D) * silu(res).
__global__ __launch_bounds__(256) void k_scan(
    const float* __restrict__ delta, const float* __restrict__ u,
    const float* __restrict__ xr,    const float* __restrict__ xdbl,
    const float* __restrict__ A_log, const float* __restrict__ Dp,
    float* __restrict__ y)
{
    int blk = blockIdx.x;            // 256 blocks
    int b   = blk >> 7;              // /128
    int d0  = (blk & 127) << 4;      // *16
    int t   = threadIdx.x;
    int cl  = t >> 4;                // channel-local 0..15
    int n   = t & 15;                // state index
    int d   = d0 + cl;

    float A_dn = -__expf(A_log[d * NS + n]);
    float Dd   = Dp[d];
    float state = 0.f;

    __shared__ float sdel[2][16][16];
    __shared__ float su_ [2][16][16];
    __shared__ float sres[2][16][16];
    __shared__ float sB_ [2][16][16];
    __shared__ float sC_ [2][16][16];

    // loader mapping: lr = timestep row, cc = column (channel or state)
    int lr = t >> 4;
    int cc = t & 15;

    float r0, r1, r2, r3, r4;
    auto prefetch = [&](int s) {
        int l = s * 16 + lr;
        size_t tok = (size_t)(b * L_ + l);
        r0 = delta[tok * DI + d0 + cc];
        r1 = u    [tok * DI + d0 + cc];
        r2 = xr   [tok * (2 * DI) + DI + d0 + cc];   // res
        r3 = xdbl [tok * 96 + 64 + cc];              // B
        r4 = xdbl [tok * 96 + 80 + cc];              // C
    };
    auto stash = [&](int buf) {
        sdel[buf][lr][cc] = r0;
        su_ [buf][lr][cc] = r1;
        sres[buf][lr][cc] = r2;
        sB_ [buf][lr][cc] = r3;
        sC_ [buf][lr][cc] = r4;
    };

    prefetch(0);
    stash(0);

    for (int s = 0; s < 64; s++) {
        __syncthreads();
        int cur = s & 1;
        if (s < 63) prefetch(s + 1);     // global loads overlap compute below
        int l0 = s * 16;
        #pragma unroll
        for (int kk = 0; kk < 16; kk++) {
            float dl = sdel[cur][kk][cl];
            float uu = su_ [cur][kk][cl];
            float dA  = __expf(dl * A_dn);
            float dBu = dl * uu * sB_[cur][kk][n];
            state = fmaf(dA, state, dBu);
            float py = state * sC_[cur][kk][n];
            py += __shfl_xor(py, 8);
            py += __shfl_xor(py, 4);
            py += __shfl_xor(py, 2);
            py += __shfl_xor(py, 1);
            if (n == 0) {
                float r  = sres[cur][kk][cl];
                float yv = (py + uu * Dd) * (r * sigmoidf_(r));
                y[(size_t)(b * L_ + l0 + kk) * DI + d] = yv;
            }
        }
        if (s < 63) {
            // buf (s+1)&1 was last read at stage s-1; barrier at loop top protects it
            stash((s + 1) & 1);
        }
    }
}

extern "C" void kernel_launch(void* const* d_in, const int* in_sizes, int n_in,
                              void* d_out, int out_size, void* d_ws, size_t ws_size,
                              hipStream_t stream)
{
    const float* x       = (const float*)d_in[0];
    const float* norm_w  = (const float*)d_in[1];
    const float* in_proj = (const float*)d_in[2];
    const float* conv_w  = (const float*)d_in[3];
    const float* conv_b  = (const float*)d_in[4];
    const float* x_proj  = (const float*)d_in[5];
    const float* dt_w    = (const float*)d_in[6];
    const float* dt_b    = (const float*)d_in[7];
    const float* A_log   = (const float*)d_in[8];
    const float* Dp      = (const float*)d_in[9];
    const float* out_w   = (const float*)d_in[10];
    float* out = (float*)d_out;
    float* ws  = (float*)d_ws;

    // workspace layout (floats); h and y share region 0 (h dead before y written)
    float* h     = ws;                 // [2048,1024]  (dead after in_proj)
    float* y     = ws;                 // [2048,2048]  gated scan output
    float* xr    = ws + 4194304;       // [2048,4096]  x_and_res
    float* u     = ws + 12582912;      // [2048,2048]
    float* xdbl  = ws + 16777216;      // [2048,96]
    float* delta = ws + 16973824;      // [2048,2048]
    // total 21,168,128 floats = ~85 MB

    // zero x_dbl for split-K atomic accumulation
    hipMemsetAsync(xdbl, 0, (size_t)TOK * 96 * sizeof(float), stream);

    // 1) RMSNorm
    k_rmsnorm<<<TOK, 256, 0, stream>>>(x, norm_w, h);

    // 2) in_proj: [2048,1024] x [4096,1024]^T -> [2048,4096]
    k_gemm_nt<0><<<dim3(64, 32, 1), 256, 0, stream>>>(
        h, DM, in_proj, DM, xr, 2 * DI, TOK, 2 * DI, DM, nullptr, nullptr);

    // 3) causal depthwise conv + SiLU -> u [2048,2048]
    k_conv_silu<<<4096, 256, 0, stream>>>(xr, conv_w, conv_b, u);

    // 4) x_proj (split-K=8, atomic): [2048,2048] x [96,2048]^T -> [2048,96]
    k_gemm_nt<3><<<dim3(2, 32, 8), 256, 0, stream>>>(
        u, DI, x_proj, DI, xdbl, 96, TOK, 96, DI / 8, nullptr, nullptr);

    // 5) dt_proj + softplus: [2048,64] x [2048,64]^T -> delta [2048,2048]
    k_gemm_nt<1><<<dim3(32, 32, 1), 256, 0, stream>>>(
        xdbl, 96, dt_w, DTR, delta, DI, TOK, DI, DTR, dt_b, nullptr);

    // 6) selective scan + gating -> y [2048,2048]
    k_scan<<<256, 256, 0, stream>>>(delta, u, xr, xdbl, A_log, Dp, y);

    // 7) out_proj + residual: [2048,2048] x [1024,2048]^T + x -> out [2048,1024]
    k_gemm_nt<2><<<dim3(16, 32, 1), 256, 0, stream>>>(
        y, DI, out_w, DI, out, DM, TOK, DM, DI, nullptr, x);
}

// Round 2
// 413.045 us; speedup vs baseline: 1.8771x; 1.8771x over previous
//
#include <hip/hip_runtime.h>
#include <hip/hip_bf16.h>
#include <math.h>

constexpr int B_   = 2;
constexpr int L_   = 1024;
constexpr int DM   = 1024;
constexpr int DI   = 2048;
constexpr int NS   = 16;
constexpr int DTR  = 64;
constexpr int TOK  = B_ * L_;

typedef __attribute__((ext_vector_type(8))) short short8;
typedef __attribute__((ext_vector_type(4))) float f32x4;
using bf16 = __hip_bfloat16;

__device__ __forceinline__ float sigmoidf_(float v) {
    return 1.f / (1.f + __expf(-v));
}
__device__ __forceinline__ float softplusf_(float v) {
    return fmaxf(v, 0.f) + __logf(1.f + __expf(-fabsf(v)));
}

__device__ __forceinline__ f32x4 mfma16(short8 a, short8 b, f32x4 c) {
    return __builtin_amdgcn_mfma_f32_16x16x32_bf16(a, b, c, 0, 0, 0);
}

// ---------------- RMSNorm -> bf16 hi/lo split ----------------
__global__ __launch_bounds__(256) void k_rmsnorm(
    const float* __restrict__ x, const float* __restrict__ w,
    bf16* __restrict__ hh, bf16* __restrict__ hl)
{
    int row = blockIdx.x;
    const float4* xrp = (const float4*)(x + (size_t)row * DM);
    float4 v = xrp[threadIdx.x];
    float ss = v.x*v.x + v.y*v.y + v.z*v.z + v.w*v.w;
    #pragma unroll
    for (int m = 32; m >= 1; m >>= 1) ss += __shfl_xor(ss, m);
    __shared__ float acc[4];
    int wid = threadIdx.x >> 6, lane = threadIdx.x & 63;
    if (lane == 0) acc[wid] = ss;
    __syncthreads();
    float tot = acc[0] + acc[1] + acc[2] + acc[3];
    float sc = rsqrtf(tot * (1.f / DM) + 1e-5f);
    float4 wv = ((const float4*)w)[threadIdx.x];
    float o[4] = { v.x*sc*wv.x, v.y*sc*wv.y, v.z*sc*wv.z, v.w*sc*wv.w };
    alignas(8) bf16 H[4], Lo[4];
    #pragma unroll
    for (int j = 0; j < 4; ++j) {
        H[j]  = __float2bfloat16(o[j]);
        Lo[j] = __float2bfloat16(o[j] - __bfloat162float(H[j]));
    }
    size_t base = (size_t)row * DM + threadIdx.x * 4;
    *(ushort4*)(hh + base) = *(ushort4*)H;
    *(ushort4*)(hl + base) = *(ushort4*)Lo;
}

// ---------------- fp32 -> bf16 hi/lo split (weights) ----------------
__global__ __launch_bounds__(256) void k_split(
    const float* __restrict__ s, bf16* __restrict__ hi, bf16* __restrict__ lo, int n4)
{
    int i = blockIdx.x * 256 + threadIdx.x;
    if (i >= n4) return;
    float4 v = ((const float4*)s)[i];
    float f[4] = { v.x, v.y, v.z, v.w };
    alignas(8) bf16 H[4], Lo[4];
    #pragma unroll
    for (int j = 0; j < 4; ++j) {
        H[j]  = __float2bfloat16(f[j]);
        Lo[j] = __float2bfloat16(f[j] - __bfloat162float(H[j]));
    }
    *(ushort4*)(hi + (size_t)i * 4) = *(ushort4*)H;
    *(ushort4*)(lo + (size_t)i * 4) = *(ushort4*)Lo;
}

// ---------------- bf16 split-GEMM via MFMA ----------------
// C[M,N] = A[M,K] * B[N,K]^T, A has NA bf16 parts, B has 2 parts.
// NA=2: Ah*Bh + Ah*Bl + Al*Bh (fp32-grade).  NA=1: A*Bh + A*Bl.
// EPI: 0 plain, 2 += resid.
// Swizzled chunk map: 16B chunk of logical (row r, kgroup g) lives at chunk
// index c = r*4 + (g ^ ((r>>1)&3)); staged via pre-swizzled global source so
// global_load_lds dest stays linear (guide rule #21); ds_read is 2-way = free.
__device__ __forceinline__ void stage_tile(const bf16* src, int ld, bf16* lds, int lane)
{
    #pragma unroll
    for (int j = 0; j < 8; ++j) {
        int c = (j << 6) + lane;
        int r = c >> 2;
        int g = (c & 3) ^ ((r >> 1) & 3);
        __builtin_amdgcn_global_load_lds(
            (const __attribute__((address_space(1))) unsigned int*)(src + (size_t)r * ld + (g << 3)),
            (__attribute__((address_space(3))) unsigned int*)(lds + (j << 9)),
            16, 0, 0);
    }
}

template<int NA, int EPI>
__global__ __launch_bounds__(256) void k_gemm_bf16(
    const bf16* __restrict__ Ah, const bf16* __restrict__ Al,
    const bf16* __restrict__ Bh, const bf16* __restrict__ Bl,
    float* __restrict__ C, const float* __restrict__ resid,
    int M, int N, int K)
{
    __shared__ alignas(1024) bf16 sA[2][NA][128 * 32];
    __shared__ alignas(1024) bf16 sB[2][2][128 * 32];

    int tid = threadIdx.x, lane = tid & 63, wv = tid >> 6;
    int bm0 = blockIdx.y * 128, bn0 = blockIdx.x * 128;
    int nkt = K >> 5;

    auto stage_all = [&](int buf, int kt) {
        int k0 = kt << 5;
        if constexpr (NA == 2) {
            if      (wv == 0) stage_tile(Ah + (size_t)bm0 * K + k0, K, &sA[buf][0][0], lane);
            else if (wv == 1) stage_tile(Al + (size_t)bm0 * K + k0, K, &sA[buf][1][0], lane);
            else if (wv == 2) stage_tile(Bh + (size_t)bn0 * K + k0, K, &sB[buf][0][0], lane);
            else              stage_tile(Bl + (size_t)bn0 * K + k0, K, &sB[buf][1][0], lane);
        } else {
            if      (wv == 0) stage_tile(Ah + (size_t)bm0 * K + k0, K, &sA[buf][0][0], lane);
            else if (wv == 1) stage_tile(Bh + (size_t)bn0 * K + k0, K, &sB[buf][0][0], lane);
            else if (wv == 2) stage_tile(Bl + (size_t)bn0 * K + k0, K, &sB[buf][1][0], lane);
        }
    };
    auto frag = [&](const bf16* t, int r, int g) -> short8 {
        int c = (r << 2) + (g ^ ((r >> 1) & 3));
        return *(const short8*)(t + (c << 3));
    };

    int wr = (wv >> 1) << 6;
    int wc = (wv & 1) << 6;
    int fr = lane & 15, g = lane >> 4;

    f32x4 acc[4][4] = {};

    stage_all(0, 0);
    __syncthreads();
    for (int kt = 0; kt < nkt; ++kt) {
        int cur = kt & 1;
        if (kt + 1 < nkt) stage_all(cur ^ 1, kt + 1);
        short8 a0[4], a1[4], b0[4], b1[4];
        #pragma unroll
        for (int m = 0; m < 4; ++m) {
            a0[m] = frag(&sA[cur][0][0], wr + m * 16 + fr, g);
            if constexpr (NA == 2) a1[m] = frag(&sA[cur][NA - 1][0], wr + m * 16 + fr, g);
        }
        #pragma unroll
        for (int n = 0; n < 4; ++n) {
            b0[n] = frag(&sB[cur][0][0], wc + n * 16 + fr, g);
            b1[n] = frag(&sB[cur][1][0], wc + n * 16 + fr, g);
        }
        #pragma unroll
        for (int m = 0; m < 4; ++m)
            #pragma unroll
            for (int n = 0; n < 4; ++n) {
                acc[m][n] = mfma16(a0[m], b0[n], acc[m][n]);
                acc[m][n] = mfma16(a0[m], b1[n], acc[m][n]);
                if constexpr (NA == 2) acc[m][n] = mfma16(a1[m], b0[n], acc[m][n]);
            }
        __syncthreads();
    }

    int rbase = bm0 + wr + (g << 2);
    int cb = bn0 + wc + fr;
    #pragma unroll
    for (int m = 0; m < 4; ++m)
        #pragma unroll
        for (int i = 0; i < 4; ++i) {
            int row = rbase + m * 16 + i;
            #pragma unroll
            for (int n = 0; n < 4; ++n) {
                int col = cb + n * 16;
                float v = acc[m][n][i];
                if constexpr (EPI == 2) v += resid[(size_t)row * N + col];
                C[(size_t)row * N + col] = v;
            }
        }
}

// ---------------- fp32 tiled GEMM (small mats): C = A * B^T ----------------
// EPI: 1 = bias+softplus, 3 = atomicAdd split-K
template<int EPI>
__global__ __launch_bounds__(256) void k_gemm_nt(
    const float* __restrict__ A, int lda,
    const float* __restrict__ Bm, int ldb,
    float* __restrict__ C, int ldc,
    int M, int N, int K_chunk,
    const float* __restrict__ bias)
{
    __shared__ float As[16][68];
    __shared__ float Bs[16][68];

    int tid = threadIdx.x;
    int m0 = blockIdx.y * 64;
    int n0 = blockIdx.x * 64;
    int kbase = blockIdx.z * K_chunk;

    int lr = tid >> 2;
    int lq = tid & 3;
    int ty = tid >> 4;
    int tx = tid & 15;

    float acc[4][4] = {};

    const float* Aptr = A + (size_t)(m0 + lr) * lda + kbase + lq * 4;
    int bn = n0 + lr;
    bool bvalid = bn < N;
    const float* Bptr = Bm + (size_t)(bvalid ? bn : 0) * ldb + kbase + lq * 4;

    for (int k0 = 0; k0 < K_chunk; k0 += 16) {
        float4 av = *(const float4*)(Aptr + k0);
        float4 bv = bvalid ? *(const float4*)(Bptr + k0)
                           : make_float4(0.f, 0.f, 0.f, 0.f);
        __syncthreads();
        As[lq*4+0][lr] = av.x; As[lq*4+1][lr] = av.y;
        As[lq*4+2][lr] = av.z; As[lq*4+3][lr] = av.w;
        Bs[lq*4+0][lr] = bv.x; Bs[lq*4+1][lr] = bv.y;
        Bs[lq*4+2][lr] = bv.z; Bs[lq*4+3][lr] = bv.w;
        __syncthreads();
        #pragma unroll
        for (int kk = 0; kk < 16; kk++) {
            float av_[4], bv_[4];
            *(float4*)av_ = *(const float4*)&As[kk][ty * 4];
            *(float4*)bv_ = *(const float4*)&Bs[kk][tx * 4];
            #pragma unroll
            for (int i = 0; i < 4; i++)
                #pragma unroll
                for (int j = 0; j < 4; j++)
                    acc[i][j] = fmaf(av_[i], bv_[j], acc[i][j]);
        }
    }

    int col = n0 + tx * 4;
    #pragma unroll
    for (int i = 0; i < 4; i++) {
        int row = m0 + ty * 4 + i;
        if constexpr (EPI == 3) {
            #pragma unroll
            for (int j = 0; j < 4; j++)
                if (col + j < N)
                    atomicAdd(&C[(size_t)row * ldc + col + j], acc[i][j]);
        } else {
            float vv[4];
            #pragma unroll
            for (int j = 0; j < 4; j++)
                vv[j] = softplusf_(acc[i][j] + bias[col + j]);
            *(float4*)&C[(size_t)row * ldc + col] = *(float4*)vv;
        }
    }
}

// ---------------- causal depthwise conv1d (K=4) + bias + SiLU ----------------
__global__ __launch_bounds__(256) void k_conv_silu(
    const float* __restrict__ xr, const float* __restrict__ w,
    const float* __restrict__ bconv, float* __restrict__ u)
{
    int idx = blockIdx.x * 256 + threadIdx.x;
    int dq = idx & 511;
    int l  = (idx >> 9) & 1023;
    int bb = idx >> 19;
    int dd = dq * 4;

    float4 wrow[4];
    #pragma unroll
    for (int j = 0; j < 4; j++)
        wrow[j] = *(const float4*)&w[(dd + j) * 4];
    float4 bias4 = *(const float4*)&bconv[dd];

    float acc[4] = { bias4.x, bias4.y, bias4.z, bias4.w };
    #pragma unroll
    for (int k = 0; k < 4; k++) {
        int lp = l - 3 + k;
        if (lp >= 0) {
            const float4 xv = *(const float4*)
                &xr[((size_t)(bb * L_ + lp)) * (2 * DI) + dd];
            const float xs_[4] = { xv.x, xv.y, xv.z, xv.w };
            #pragma unroll
            for (int j = 0; j < 4; j++)
                acc[j] = fmaf(xs_[j], ((const float*)&wrow[j])[k], acc[j]);
        }
    }
    float out[4];
    #pragma unroll
    for (int j = 0; j < 4; j++)
        out[j] = acc[j] * sigmoidf_(acc[j]);
    *(float4*)&u[((size_t)(bb * L_ + l)) * DI + dd] = *(float4*)out;
}

// ---------------- chunked selective scan ----------------
// NC=8 chunks of 128 steps. Pass A: per-chunk local scan (P=prod dA, S=local state).
__global__ __launch_bounds__(256) void k_scan_part(
    const float* __restrict__ delta, const float* __restrict__ u,
    const float* __restrict__ xdbl, const float* __restrict__ A_log,
    float* __restrict__ P, float* __restrict__ S)
{
    int bx = blockIdx.x;              // 2048
    int c  = bx & 7;
    int rest = bx >> 3;
    int b  = rest >> 7;
    int d0 = (rest & 127) << 4;
    int t = threadIdx.x;
    int cl = t >> 4, n = t & 15;
    int d = d0 + cl;

    float A_dn = -__expf(A_log[d * NS + n]);
    float p = 1.f, s = 0.f;
    size_t tokbase = (size_t)b * L_ + (c << 7);
    #pragma unroll 4
    for (int k = 0; k < 128; ++k) {
        size_t tok = tokbase + k;
        float dl = delta[tok * DI + d];
        float uu = u[tok * DI + d];
        float Bv = xdbl[tok * 96 + 64 + n];
        float dA = __expf(dl * A_dn);
        s = fmaf(dA, s, dl * uu * Bv);
        p *= dA;
    }
    size_t o = ((((size_t)b * 8 + c) * DI) + d) * NS + n;
    P[o] = p; S[o] = s;
}

// Pass B: sequential chunk combine -> per-chunk initial states.
__global__ __launch_bounds__(256) void k_scan_comb(
    const float* __restrict__ P, const float* __restrict__ S,
    float* __restrict__ init)
{
    int idx = blockIdx.x * 256 + threadIdx.x;  // 65536
    int n = idx & 15;
    int d = (idx >> 4) & (DI - 1);
    int b = idx >> 15;
    float carry = 0.f;
    #pragma unroll
    for (int c = 0; c < 8; ++c) {
        size_t o = ((((size_t)b * 8 + c) * DI) + d) * NS + n;
        init[o] = carry;
        carry = fmaf(P[o], carry, S[o]);
    }
}

// Pass C: re-scan with correct init; y = (scan + u*D) * silu(res), bf16 out.
__global__ __launch_bounds__(256) void k_scan_y(
    const float* __restrict__ delta, const float* __restrict__ u,
    const float* __restrict__ xdbl, const float* __restrict__ xr,
    const float* __restrict__ A_log, const float* __restrict__ Dp,
    const float* __restrict__ init, bf16* __restrict__ y)
{
    int bx = blockIdx.x;
    int c  = bx & 7;
    int rest = bx >> 3;
    int b  = rest >> 7;
    int d0 = (rest & 127) << 4;
    int t = threadIdx.x;
    int cl = t >> 4, n = t & 15;
    int d = d0 + cl;

    float A_dn = -__expf(A_log[d * NS + n]);
    float Dd = Dp[d];
    size_t o = ((((size_t)b * 8 + c) * DI) + d) * NS + n;
    float s = init[o];
    size_t tokbase = (size_t)b * L_ + (c << 7);
    #pragma unroll 4
    for (int k = 0; k < 128; ++k) {
        size_t tok = tokbase + k;
        float dl = delta[tok * DI + d];
        float uu = u[tok * DI + d];
        float Bv = xdbl[tok * 96 + 64 + n];
        float Cv = xdbl[tok * 96 + 80 + n];
        float dA = __expf(dl * A_dn);
        s = fmaf(dA, s, dl * uu * Bv);
        float py = s * Cv;
        py += __shfl_xor(py, 1);
        py += __shfl_xor(py, 2);
        py += __shfl_xor(py, 4);
        py += __shfl_xor(py, 8);
        if (n == 0) {
            float r = xr[tok * (2 * DI) + DI + d];
            float yv = fmaf(uu, Dd, py) * (r * sigmoidf_(r));
            y[tok * DI + d] = __float2bfloat16(yv);
        }
    }
}

extern "C" void kernel_launch(void* const* d_in, const int* in_sizes, int n_in,
                              void* d_out, int out_size, void* d_ws, size_t ws_size,
                              hipStream_t stream)
{
    const float* x       = (const float*)d_in[0];
    const float* norm_w  = (const float*)d_in[1];
    const float* in_proj = (const float*)d_in[2];
    const float* conv_w  = (const float*)d_in[3];
    const float* conv_b  = (const float*)d_in[4];
    const float* x_proj  = (const float*)d_in[5];
    const float* dt_w    = (const float*)d_in[6];
    const float* dt_b    = (const float*)d_in[7];
    const float* A_log   = (const float*)d_in[8];
    const float* Dp      = (const float*)d_in[9];
    const float* out_w   = (const float*)d_in[10];
    float* out = (float*)d_out;

    // ---- workspace layout (byte offsets; lifetime-aliased; total 80 MB) ----
    constexpr size_t MB = 1u << 20;
    char* Wb = (char*)d_ws;
    float* xr    = (float*)(Wb + 0);        // [2048,4096] f32, 32MB; alive in_proj..scan_y
    bf16*  h_h   = (bf16*) (Wb + 32 * MB);  // [2048,1024] 4MB  } dead after in_proj,
    bf16*  h_l   = (bf16*) (Wb + 36 * MB);  // [2048,1024] 4MB  } then u overwrites
    float* u     = (float*)(Wb + 32 * MB);  // [2048,2048] f32 16MB; conv..scan_y
    float* delta = (float*)(Wb + 48 * MB);  // [2048,2048] f32 16MB; dt..scan_y
    bf16*  wo_h  = (bf16*) (Wb + 48 * MB);  // [1024,2048] 4MB  } overwrite delta
    bf16*  wo_l  = (bf16*) (Wb + 52 * MB);  // [1024,2048] 4MB  } after scan_y
    bf16*  wi_h  = (bf16*) (Wb + 64 * MB);  // [4096,1024] 8MB } dead after in_proj
    bf16*  wi_l  = (bf16*) (Wb + 72 * MB);  // [4096,1024] 8MB }
    float* Pbuf  = (float*)(Wb + 64 * MB);  // [2,8,2048,16] 2MB
    float* Sbuf  = (float*)(Wb + 66 * MB);  // 2MB
    bf16*  y_h   = (bf16*) (Wb + 68 * MB);  // [2048,2048] bf16 8MB
    float* initb = (float*)(Wb + 76 * MB);  // 2MB
    float* xdbl  = (float*)(Wb + 78 * MB);  // [2048,96] 0.75MB

    // 1) RMSNorm -> h hi/lo
    k_rmsnorm<<<TOK, 256, 0, stream>>>(x, norm_w, h_h, h_l);
    // 2) split in_proj weights
    k_split<<<4096, 256, 0, stream>>>(in_proj, wi_h, wi_l, (2 * DI * DM) / 4);
    // 3) in_proj: [2048,1024] x [4096,1024]^T -> xr  (bf16x3 MFMA)
    k_gemm_bf16<2, 0><<<dim3(32, 16), 256, 0, stream>>>(
        h_h, h_l, wi_h, wi_l, xr, nullptr, TOK, 2 * DI, DM);
    // 4) conv + SiLU -> u (overwrites h region; h dead)
    k_conv_silu<<<4096, 256, 0, stream>>>(xr, conv_w, conv_b, u);
    // 5) x_proj split-K=8 atomic (xdbl overlaps dead wi_l tail; memset here)
    hipMemsetAsync(xdbl, 0, (size_t)TOK * 96 * sizeof(float), stream);
    k_gemm_nt<3><<<dim3(2, 32, 8), 256, 0, stream>>>(
        u, DI, x_proj, DI, xdbl, 96, TOK, 96, DI / 8, nullptr);
    // 6) dt_proj + softplus -> delta
    k_gemm_nt<1><<<dim3(32, 32, 1), 256, 0, stream>>>(
        xdbl, 96, dt_w, DTR, delta, DI, TOK, DI, DTR, dt_b);
    // 7) chunked scan: partials -> combine -> y (bf16)
    k_scan_part<<<2048, 256, 0, stream>>>(delta, u, xdbl, A_log, Pbuf, Sbuf);
    k_scan_comb<<<256, 256, 0, stream>>>(Pbuf, Sbuf, initb);
    k_scan_y<<<2048, 256, 0, stream>>>(delta, u, xdbl, xr, A_log, Dp, initb, y_h);
    // 8) split out_proj weights (overwrites delta; delta dead)
    k_split<<<2048, 256, 0, stream>>>(out_w, wo_h, wo_l, (DM * DI) / 4);
    // 9) out_proj + residual: y_h x [1024,2048]^T + x -> out (bf16x2 MFMA)
    k_gemm_bf16<1, 2><<<dim3(8, 16), 256, 0, stream>>>(
        y_h, nullptr, wo_h, wo_l, out, x, TOK, DM, DI);
}